// Round 8
// baseline (243.881 us; speedup 1.0000x reference)
//
#include <hip/hip_runtime.h>

// VQ layer, two-pass certified scheme, single bf16x3 packed codebook.
// score(t,k) = z_t.e_k - 0.5||e_k||^2 ; argmax_k == argmin_k ||z_t-e_k||^2.
//
// Pass 1 (MFMA, bf16x2 3-term, -0.5||e||^2 folded into acc init):
//   eps_hard <= ~3.2e-4. Top-2 per token; gap >= DELTA=5e-3 certifies the
//   winner == true fp32 argmin (empirically validated in Round 7).
//   In-block codebook split: waves 0-3 = codes 0-2047, waves 4-7 = 2048-4095,
//   LDS merge at end -> 4 waves/SIMD (vs 2) at identical per-CU pipe work.
// Pass 2 (MFMA, bf16x3 6-term == Round-5 numerics, absmax 0.0 proven):
//   uncertain tokens in 16-token tiles; 4 waves split codebook; two
//   independent 6-MFMA chains summed in fp32 (halves dependent latency).
//
// d_ws: [0,1.5MB)         emb B-fragments, bf16 3-level, frag-linear
//       [OFF_N,+16KB)     NEGATIVE half-norms: -0.5||e||^2 fp32 per code
//       [OFF_CNT]         u32 uncertain counter (init by pack kernel)
//       [OFF_LIST,+256KB) u32 uncertain-token list (capacity 65536 = max)
// Fallback to pure-fp32 kernel if ws_size too small.

typedef __attribute__((ext_vector_type(8))) short short8;
typedef __attribute__((ext_vector_type(4))) float f32x4;
typedef unsigned int u32;
typedef __attribute__((address_space(3))) u32 lds_u32;
typedef const __attribute__((address_space(1))) u32 glb_u32;

#define NCHUNK 256                         // 4096 codes / 16 per chunk
#define FRAGS 6                            // 3 levels x 2 K-halves
#define CHUNK_WSB (FRAGS * 64 * 16)        // 6144 B per chunk in ws
#define CHUNK_LDS 4096                     // levels 1-2 only staged in pass 1
#define GROUP2 2                           // chunks staged per barrier per half
#define GB2 (GROUP2 * CHUNK_LDS)           // 8 KB
#define NG2 64                             // groups per half (128 chunks / 2)
#define WSB_BYTES (NCHUNK * CHUNK_WSB)     // 1,572,864
#define OFF_N    WSB_BYTES
#define OFF_CNT  (OFF_N + 16384)
#define OFF_LIST (OFF_CNT + 64)
#define WS_NEEDED ((size_t)OFF_LIST + 65536u * 4u)   // ~1.77 MB
#define DELTA 0.005f

static __device__ __forceinline__ unsigned short f2bf(float f) {
    u32 u = __builtin_bit_cast(u32, f);
    u += 0x7fffu + ((u >> 16) & 1u);       // RNE; inputs finite Gaussians
    return (unsigned short)(u >> 16);
}
static __device__ __forceinline__ float bf2f(unsigned short h) {
    u32 u = ((u32)h) << 16;
    return __builtin_bit_cast(float, u);
}

// ---- prep: pack emb into 3-level bf16 B-fragments + neg-norms + counter --
// 16B-group id = (ck*6 + f)*64 + lane;  f = level*2 + s (s = K-half).
// B-frag (16x16x32): n = lane&15, k = s*32 + (lane>>4)*8 + j.
__global__ void vq_pack_kernel(const float* __restrict__ emb,
                               unsigned short* __restrict__ wsB,
                               float* __restrict__ wsN,
                               u32* __restrict__ wsCnt) {
    int ck    = blockIdx.x;                // 256 blocks x 384 threads
    int f     = threadIdx.x >> 6;
    int lane  = threadIdx.x & 63;
    int level = f >> 1, s = f & 1;
    int code  = ck * 16 + (lane & 15);
    int kb    = s * 32 + (lane >> 4) * 8;
    const float* src = emb + code * 64 + kb;
    short8 o;
#pragma unroll
    for (int j = 0; j < 8; ++j) {
        float x = src[j];
        unsigned short h1 = f2bf(x);
        float r1 = x - bf2f(h1);
        unsigned short h2 = f2bf(r1);
        float r2 = r1 - bf2f(h2);
        unsigned short h3 = f2bf(r2);
        o[j] = (short)(level == 0 ? h1 : (level == 1 ? h2 : h3));
    }
    ((short8*)wsB)[(ck * FRAGS + f) * 64 + lane] = o;

    if (threadIdx.x < 16) {                // exact fp32 NEGATIVE half-norms
        int c = ck * 16 + threadIdx.x;
        const float* e = emb + c * 64;
        float ssum = 0.f;
#pragma unroll
        for (int k = 0; k < 64; ++k) { float v = e[k]; ssum = fmaf(v, v, ssum); }
        wsN[c] = -0.5f * ssum;
    }
    if (ck == 0 && threadIdx.x == 0) *wsCnt = 0u;
}

// ---- pass 1: bf16x2 3-term MFMA, split codebook in-block -----------------
// 512 blocks x 512 threads (8 waves). Block owns 128 tokens; wave (h,ws):
// tokens [ws*32, ws*32+32) vs codes [h*2048, h*2048+2048).
__global__ __launch_bounds__(512, 4) void vq_main_kernel(
    const float* __restrict__ z, const float* __restrict__ emb,
    const unsigned short* __restrict__ wsB, const float* __restrict__ wsN,
    u32* __restrict__ wsCnt, u32* __restrict__ wsList,
    float* __restrict__ out)
{
    __shared__ char  sB[2][2][GB2];        // [half][buf][8KB] double buffer
    __shared__ float sNall[4096];          // all -0.5||e||^2, staged once
    __shared__ float sS1[2][128], sS2[2][128];
    __shared__ int   sI1[2][128];
    __shared__ int   sOut[128];

    const int wave = threadIdx.x >> 6;     // 0..7
    const int lane = threadIdx.x & 63;
    const int quad = lane >> 4;
    const int col  = lane & 15;
    const int half = wave >> 2;
    const int wsub = wave & 3;

    // stage all 16 KB of neg-norms once (16 x 1KB ops, 2 per wave)
    {
        const char* gp = (const char*)wsN;
        char*       lp = (char*)sNall;
#pragma unroll
        for (int i = 0; i < 2; ++i) {
            int off = (wave * 2 + i) * 1024;
            __builtin_amdgcn_global_load_lds((glb_u32*)(gp + off + lane * 16),
                                             (lds_u32*)(lp + off), 16, 0, 0);
        }
    }

    // A fragments, bf16 2-level: a[tile][level][khalf], k = kh*32+quad*8+j
    const int t0 = blockIdx.x * 128 + wsub * 32;
    short8 a[2][2][2];
#pragma unroll
    for (int t = 0; t < 2; ++t) {
        const int tok = t0 + t * 16 + col;
        const int b   = tok >> 12;
        const int hw  = tok & 4095;
        const float* zp = z + b * 262144 + hw;
#pragma unroll
        for (int s = 0; s < 2; ++s)
#pragma unroll
            for (int j = 0; j < 8; ++j) {
                int k = s * 32 + quad * 8 + j;
                float x = zp[k * 4096];    // coalesced over col lanes
                unsigned short h1 = f2bf(x);
                a[t][0][s][j] = (short)h1;
                a[t][1][s][j] = (short)f2bf(x - bf2f(h1));
            }
    }

    float best[2][4], best2[2][4];
    int   bidx[2][4];
#pragma unroll
    for (int t = 0; t < 2; ++t)
#pragma unroll
        for (int r = 0; r < 4; ++r) {
            best[t][r] = -3.4e38f; best2[t][r] = -3.4e38f; bidx[t][r] = 0;
        }

    // stage one 8 KB group for this half: waves wsub<2 copy chunk wsub
    auto stage = [&](int buf, int g) {
        if (wsub < GROUP2) {
            const char* gbase = (const char*)wsB +
                (size_t)(half * 128 + g * GROUP2 + wsub) * CHUNK_WSB;
            char* lbase = sB[half][buf] + wsub * CHUNK_LDS;
#pragma unroll
            for (int i = 0; i < 4; ++i)
                __builtin_amdgcn_global_load_lds(
                    (glb_u32*)(gbase + i * 1024 + lane * 16),
                    (lds_u32*)(lbase + i * 1024), 16, 0, 0);
        }
    };

    stage(0, 0);

    for (int g = 0; g < NG2; ++g) {
        const int cur = g & 1;
        __syncthreads();                   // group g (and norms) landed
        if (g + 1 < NG2) stage(cur ^ 1, g + 1);

#pragma unroll
        for (int cl = 0; cl < GROUP2; ++cl) {
            const int ck = half * 128 + g * GROUP2 + cl;
            const char* base = sB[half][cur] + cl * CHUNK_LDS;
            short8 b10 = ((const short8*)(base + 0 * 1024))[lane]; // g1 kh0
            short8 b11 = ((const short8*)(base + 1 * 1024))[lane]; // g1 kh1
            short8 b20 = ((const short8*)(base + 2 * 1024))[lane]; // g2 kh0
            short8 b21 = ((const short8*)(base + 3 * 1024))[lane]; // g2 kh1
            const float nnrm = sNall[ck * 16 + col];   // -0.5||e||^2
            const int   code = ck * 16 + col;

#pragma unroll
            for (int t = 0; t < 2; ++t) {
                f32x4 acc = {nnrm, nnrm, nnrm, nnrm};  // fold neg-norm
                acc = __builtin_amdgcn_mfma_f32_16x16x32_bf16(a[t][1][0], b10, acc, 0, 0, 0);
                acc = __builtin_amdgcn_mfma_f32_16x16x32_bf16(a[t][1][1], b11, acc, 0, 0, 0);
                acc = __builtin_amdgcn_mfma_f32_16x16x32_bf16(a[t][0][0], b20, acc, 0, 0, 0);
                acc = __builtin_amdgcn_mfma_f32_16x16x32_bf16(a[t][0][1], b21, acc, 0, 0, 0);
                acc = __builtin_amdgcn_mfma_f32_16x16x32_bf16(a[t][0][0], b10, acc, 0, 0, 0);
                acc = __builtin_amdgcn_mfma_f32_16x16x32_bf16(a[t][0][1], b11, acc, 0, 0, 0);

#pragma unroll
                for (int r = 0; r < 4; ++r) {
                    float sc = acc[r];
                    best2[t][r] = fmaxf(best2[t][r], fminf(sc, best[t][r]));
                    bool gt = sc > best[t][r];
                    bidx[t][r] = gt ? code : bidx[t][r];
                    best[t][r] = fmaxf(best[t][r], sc);
                }
            }
        }
    }

    // top-2 merge across the 16 cols of each quad group
#pragma unroll
    for (int off = 1; off < 16; off <<= 1)
#pragma unroll
        for (int t = 0; t < 2; ++t)
#pragma unroll
            for (int r = 0; r < 4; ++r) {
                float os1 = __shfl_xor(best[t][r],  off, 64);
                int   oi1 = __shfl_xor(bidx[t][r],  off, 64);
                float os2 = __shfl_xor(best2[t][r], off, 64);
                bool take = (os1 > best[t][r]) ||
                            (os1 == best[t][r] && oi1 < bidx[t][r]);
                float ns2 = take ? fmaxf(best[t][r], os2)
                                 : fmaxf(best2[t][r], os1);
                if (take) { best[t][r] = os1; bidx[t][r] = oi1; }
                best2[t][r] = ns2;
            }
    if (col == 0)
#pragma unroll
        for (int t = 0; t < 2; ++t)
#pragma unroll
            for (int r = 0; r < 4; ++r) {
                int tokb = wsub * 32 + t * 16 + quad * 4 + r;
                sS1[half][tokb] = best[t][r];
                sS2[half][tokb] = best2[t][r];
                sI1[half][tokb] = bidx[t][r];
            }
    __syncthreads();

    // combine halves per token; emit uncertain list
    if (threadIdx.x < 128) {
        const int tk = threadIdx.x;
        float b0 = sS1[0][tk], b1 = sS1[1][tk];
        int   i0 = sI1[0][tk], i1 = sI1[1][tk];
        float q0 = sS2[0][tk], q1 = sS2[1][tk];
        bool take1 = b1 > b0;              // tie -> half0 (lower idx)
        float bw = take1 ? b1 : b0;
        float bl = take1 ? b0 : b1;
        float qw = take1 ? q1 : q0;
        sOut[tk] = take1 ? i1 : i0;
        float second = fmaxf(qw, bl);      // exact global runner-up bound
        if (bw - second < DELTA) {
            u32 slot = atomicAdd(wsCnt, 1u);
            wsList[slot] = (u32)(blockIdx.x * 128 + tk);
        }
    }
    __syncthreads();

    // gather-write: 512 threads = 128 tokens x 4 channel-groups of 16
    const int tk   = threadIdx.x & 127;
    const int coff = (threadIdx.x >> 7) * 16;
    const int gt   = blockIdx.x * 128 + tk;
    const int ob   = gt >> 12, ohw = gt & 4095;
    float* op = out + ob * 262144 + ohw;
    const float4* ep = (const float4*)(emb + sOut[tk] * 64 + coff);
#pragma unroll
    for (int i = 0; i < 4; ++i) {
        float4 v = ep[i];
        op[(coff + 4 * i + 0) * 4096] = v.x;
        op[(coff + 4 * i + 1) * 4096] = v.y;
        op[(coff + 4 * i + 2) * 4096] = v.z;
        op[(coff + 4 * i + 3) * 4096] = v.w;
    }
}

// ---- pass 2: MFMA bf16x3 6-term repair, two independent chains -----------
// 128 blocks x 256 threads; one 16-token tile per iteration; wave w scores
// chunks [w*64, w*64+64); B-frags read coalesced from packed ws.
__global__ __launch_bounds__(256) void vq_fix_kernel(
    const float* __restrict__ z, const float* __restrict__ emb,
    const unsigned short* __restrict__ wsB, const float* __restrict__ wsN,
    const u32* __restrict__ wsCnt, const u32* __restrict__ wsList,
    float* __restrict__ out)
{
    __shared__ float sS[4][16];
    __shared__ int   sI[4][16];
    __shared__ int   sTok[16];

    const int wave = threadIdx.x >> 6;
    const int lane = threadIdx.x & 63;
    const int quad = lane >> 4;
    const int col  = lane & 15;
    const u32 count = *wsCnt;
    const u32 tiles = (count + 15u) >> 4;

    for (u32 T = blockIdx.x; T < tiles; T += gridDim.x) {
        if (threadIdx.x < 16) {
            u32 slot = T * 16 + threadIdx.x;
            if (slot >= count) slot = count - 1;     // duplicates benign
            sTok[threadIdx.x] = (int)wsList[slot];
        }
        __syncthreads();

        const int tok = sTok[col];
        const int b   = tok >> 12;
        const int hw  = tok & 4095;
        const float* zp = z + b * 262144 + hw;
        short8 a[3][2];
#pragma unroll
        for (int s = 0; s < 2; ++s)
#pragma unroll
            for (int j = 0; j < 8; ++j) {
                int k = s * 32 + quad * 8 + j;
                float x = zp[k * 4096];
                unsigned short h1 = f2bf(x);
                float r1 = x - bf2f(h1);
                unsigned short h2 = f2bf(r1);
                float r2 = r1 - bf2f(h2);
                a[0][s][j] = (short)h1;
                a[1][s][j] = (short)h2;
                a[2][s][j] = (short)f2bf(r2);
            }

        float best[4] = {-3.4e38f, -3.4e38f, -3.4e38f, -3.4e38f};
        int   bidx[4] = {0, 0, 0, 0};

        const short8* Bg = (const short8*)wsB;
        for (int ck = wave * 64; ck < wave * 64 + 64; ++ck) {
            const int fb = ck * FRAGS * 64;
            short8 b10 = Bg[fb + 0 * 64 + lane];
            short8 b11 = Bg[fb + 1 * 64 + lane];
            short8 b20 = Bg[fb + 2 * 64 + lane];
            short8 b21 = Bg[fb + 3 * 64 + lane];
            short8 b30 = Bg[fb + 4 * 64 + lane];
            short8 b31 = Bg[fb + 5 * 64 + lane];
            const float nnrm = wsN[ck * 16 + col];   // -0.5||e||^2
            const int   code = ck * 16 + col;

            // chain A: 2^-18-class terms; chain B: 2^-9 + main. Independent.
            f32x4 accA = {0.f, 0.f, 0.f, 0.f};
            f32x4 accB = {0.f, 0.f, 0.f, 0.f};
            accA = __builtin_amdgcn_mfma_f32_16x16x32_bf16(a[1][0], b20, accA, 0, 0, 0);
            accB = __builtin_amdgcn_mfma_f32_16x16x32_bf16(a[0][0], b20, accB, 0, 0, 0);
            accA = __builtin_amdgcn_mfma_f32_16x16x32_bf16(a[1][1], b21, accA, 0, 0, 0);
            accB = __builtin_amdgcn_mfma_f32_16x16x32_bf16(a[0][1], b21, accB, 0, 0, 0);
            accA = __builtin_amdgcn_mfma_f32_16x16x32_bf16(a[0][0], b30, accA, 0, 0, 0);
            accB = __builtin_amdgcn_mfma_f32_16x16x32_bf16(a[1][0], b10, accB, 0, 0, 0);
            accA = __builtin_amdgcn_mfma_f32_16x16x32_bf16(a[0][1], b31, accA, 0, 0, 0);
            accB = __builtin_amdgcn_mfma_f32_16x16x32_bf16(a[1][1], b11, accB, 0, 0, 0);
            accA = __builtin_amdgcn_mfma_f32_16x16x32_bf16(a[2][0], b10, accA, 0, 0, 0);
            accB = __builtin_amdgcn_mfma_f32_16x16x32_bf16(a[0][0], b10, accB, 0, 0, 0);
            accA = __builtin_amdgcn_mfma_f32_16x16x32_bf16(a[2][1], b11, accA, 0, 0, 0);
            accB = __builtin_amdgcn_mfma_f32_16x16x32_bf16(a[0][1], b11, accB, 0, 0, 0);

#pragma unroll
            for (int r = 0; r < 4; ++r) {
                float score = (accA[r] + accB[r]) + nnrm;
                if (score > best[r]) { best[r] = score; bidx[r] = code; }
            }
        }

#pragma unroll
        for (int off = 1; off < 16; off <<= 1)
#pragma unroll
            for (int r = 0; r < 4; ++r) {
                float os = __shfl_xor(best[r], off, 64);
                int   oi = __shfl_xor(bidx[r], off, 64);
                if (os > best[r] || (os == best[r] && oi < bidx[r])) {
                    best[r] = os; bidx[r] = oi;
                }
            }
        if (col == 0)
#pragma unroll
            for (int r = 0; r < 4; ++r) {
                sS[wave][quad * 4 + r] = best[r];
                sI[wave][quad * 4 + r] = bidx[r];
            }
        __syncthreads();

        if (threadIdx.x < 16) {            // waves cover ascending ranges
            float bs = sS[0][threadIdx.x]; int bi = sI[0][threadIdx.x];
#pragma unroll
            for (int w = 1; w < 4; ++w) {
                float s2 = sS[w][threadIdx.x]; int i2 = sI[w][threadIdx.x];
                if (s2 > bs || (s2 == bs && i2 < bi)) { bs = s2; bi = i2; }
            }
            sI[0][threadIdx.x] = bi;
        }
        __syncthreads();

        {
            const int row = threadIdx.x & 15;
            const int cb  = (threadIdx.x >> 4) * 4;
            const int tk2 = sTok[row];
            const int bb  = tk2 >> 12, hh = tk2 & 4095;
            const float* e = emb + sI[0][row] * 64;
            float* op = out + bb * 262144 + hh;
#pragma unroll
            for (int i = 0; i < 4; ++i)
                op[(cb + i) * 4096] = e[cb + i];
        }
        __syncthreads();
    }
}

// ---- fallback (proven Round-1 kernel; used only if ws is too small) ------
__global__ __launch_bounds__(256) void vq_fp32_kernel(
    const float* __restrict__ z, const float* __restrict__ emb,
    float* __restrict__ out)
{
    __shared__ float se[64 * 64];
    __shared__ float snorm[64];

    const int t  = blockIdx.x * 256 + threadIdx.x;
    const int b  = t >> 12;
    const int hw = t & 4095;
    const float* zt = z + (size_t)b * 262144 + hw;
    float zf[64];
#pragma unroll
    for (int c = 0; c < 64; ++c) zf[c] = zt[(size_t)c * 4096];

    float best = -3.4e38f;
    int   bestIdx = 0;
    for (int k0 = 0; k0 < 4096; k0 += 64) {
        __syncthreads();
        const float4* src = (const float4*)(emb + (size_t)k0 * 64);
        float4*       dst = (float4*)se;
#pragma unroll
        for (int i = 0; i < 4; ++i)
            dst[i * 256 + threadIdx.x] = src[i * 256 + threadIdx.x];
        __syncthreads();
        if (threadIdx.x < 64) {
            float s = 0.f;
#pragma unroll
            for (int c = 0; c < 64; ++c) {
                float v = se[threadIdx.x * 64 + c];
                s = fmaf(v, v, s);
            }
            snorm[threadIdx.x] = 0.5f * s;
        }
        __syncthreads();
#pragma unroll 4
        for (int kk = 0; kk < 64; ++kk) {
            float dot = 0.f;
#pragma unroll
            for (int c = 0; c < 64; ++c)
                dot = fmaf(zf[c], se[kk * 64 + c], dot);
            float score = dot - snorm[kk];
            if (score > best) { best = score; bestIdx = k0 + kk; }
        }
    }
    const float* e  = emb + (size_t)bestIdx * 64;
    float*       ot = out + (size_t)b * 262144 + hw;
#pragma unroll
    for (int c = 0; c < 64; ++c) ot[(size_t)c * 4096] = e[c];
}

extern "C" void kernel_launch(void* const* d_in, const int* in_sizes, int n_in,
                              void* d_out, int out_size, void* d_ws, size_t ws_size,
                              hipStream_t stream) {
    const float* z   = (const float*)d_in[0];
    const float* emb = (const float*)d_in[1];
    float*       out = (float*)d_out;

    if (ws_size < WS_NEEDED) {          // constant per session: graph-safe
        vq_fp32_kernel<<<256, 256, 0, stream>>>(z, emb, out);
        return;
    }

    unsigned short* wsB   = (unsigned short*)d_ws;
    float*          wsN   = (float*)((char*)d_ws + OFF_N);
    u32*            wsCnt = (u32*)((char*)d_ws + OFF_CNT);
    u32*            wsList= (u32*)((char*)d_ws + OFF_LIST);

    vq_pack_kernel<<<256, 384, 0, stream>>>(emb, wsB, wsN, wsCnt);
    vq_main_kernel<<<512, 512, 0, stream>>>(z, emb, wsB, wsN, wsCnt, wsList, out);
    vq_fix_kernel<<<128, 256, 0, stream>>>(z, emb, wsB, wsN, wsCnt, wsList, out);
}